// Round 9
// baseline (51.601 us; speedup 1.0000x reference)
//
#include <hip/hip_runtime.h>
#include <hip/hip_bf16.h>
#include <math.h>

typedef __attribute__((ext_vector_type(4))) float f32x4;
typedef __attribute__((ext_vector_type(8))) short bf16x8;

#define NB    64
#define LQ    32
#define LDOC  256
#define HDIM  768
#define DDIM  128
#define NTOK_Q (NB * LQ)        // 2048
#define NTOK_D (NB * LDOC)      // 16384
#define NTOK   (NTOK_Q + NTOK_D) // 18432

// ws layout (bytes):
#define WS_OFF_W    0           // Wbf   : 128*768 bf16   (196608)
#define WS_OFF_MASK 196608      // maskT : 64*16 ushort (2KB)
#define WS_OFF_QN   212992      // Qn    : 2048*128 bf16
#define WS_OFF_DN   737280      // Dn    : 16384*128 bf16 (ends 4931584)
#define WS_OFF_AH   4931584     // Ah    : 18432*768 bf16 (28.3MB)

__device__ inline short f2bf(float f) {
    unsigned u = __float_as_uint(f);
    u = (u + 0x7fffu + ((u >> 16) & 1u)) >> 16;   // RNE
    return (short)u;
}

// ---------------------------------------------------------------------------
// convert_prep: blocks 0..1727 stream-convert Q/D hidden fp32 -> bf16 Ah with
// maximal TLP (8 independent coalesced float4 loads/thread, no barriers);
// blocks 1728..1823 convert W; block 1824 builds the bit-transposed mask.
__global__ __launch_bounds__(256)
void convert_prep(const float* __restrict__ Qh, const float* __restrict__ Dh,
                  const float* __restrict__ W,
                  short* __restrict__ Ah, short* __restrict__ Wbf,
                  const unsigned char* __restrict__ mraw,
                  unsigned short* __restrict__ maskT) {
    const int bid = blockIdx.x;
    const int tid = threadIdx.x;
    if (bid < 1728) {
        // 3,538,944 float4 units total; block owns 2048 consecutive units.
        const size_t QU = (size_t)NTOK_Q * HDIM / 4;   // 393216 (exact split)
#pragma unroll
        for (int it = 0; it < 2; ++it) {
#pragma unroll
            for (int j = 0; j < 4; ++j) {
                const size_t u = (size_t)bid * 2048 + it * 1024 + j * 256 + tid;
                const float* s = (u < QU) ? (Qh + u * 4) : (Dh + (u - QU) * 4);
                float4 v = *(const float4*)s;
                short4 o;
                o.x = f2bf(v.x); o.y = f2bf(v.y); o.z = f2bf(v.z); o.w = f2bf(v.w);
                *(short4*)(Ah + u * 4) = o;
            }
        }
        return;
    }
    if (bid < 1824) {
        int i = (bid - 1728) * 256 + tid;
        float4 v = *(const float4*)(W + (size_t)i * 4);
        short4 o;
        o.x = f2bf(v.x); o.y = f2bf(v.y); o.z = f2bf(v.z); o.w = f2bf(v.w);
        *(short4*)(Wbf + (size_t)i * 4) = o;
        return;
    }
    // mask block: detect 1B vs 4B layout from data (deterministic), bit-pack
    __shared__ int dword_ok_s;
    if (tid == 0) dword_ok_s = 1;
    __syncthreads();
    const unsigned* dw = (const unsigned*)mraw;
    int ok = 1;
    for (int i = tid; i < 4096; i += 256) {   // first 16KB: safe both layouts
        unsigned v = dw[i];
        if (!(v == 0u || v == 1u || v == 0x3F800000u)) ok = 0;
    }
    if (!ok) atomicAnd(&dword_ok_s, 0);
    __syncthreads();
    const int isdw = dword_ok_s;
    for (int w = tid; w < 1024; w += 256) {   // word w: c=w>>4, lane-col=w&15
        const int c = w >> 4, lcc = w & 15;
        unsigned bits = 0;
        if (isdw) {
            for (int nt = 0; nt < 16; ++nt)
                bits |= (dw[c * 256 + nt * 16 + lcc] ? 1u : 0u) << nt;
        } else {
            for (int nt = 0; nt < 16; ++nt)
                bits |= (mraw[c * 256 + nt * 16 + lcc] ? 1u : 0u) << nt;
        }
        maskT[w] = (unsigned short)bits;
    }
}

// ---------------------------------------------------------------------------
// proj GEMM v9: round-6 2-phase structure, A already bf16 (L3-hot from
// convert). Block = 32 rows x 128 cols, BK=64, 12 steps, 4 waves (2x2 of
// 16x64). A-stage 4KB/step (1 vm-instr/wave), B-stage 16KB. LDS 40KB ->
// 4 blocks/CU. No f2bf in the K-loop (A frags are raw bf16x8 LDS reads).
__global__ __launch_bounds__(256)
void proj_gemm(const short* __restrict__ Ah, const short* __restrict__ Wbf,
               short* __restrict__ Qn, short* __restrict__ Dn) {
    const int tid  = threadIdx.x;
    const int lane = tid & 63;
    const int wave = tid >> 6;
    const int g    = lane >> 4;
    const int lc   = lane & 15;
    const int wr   = wave >> 1;          // 16-row half
    const int wc   = wave & 1;           // 64-col half
    const int row0 = blockIdx.x * 32;

    __shared__ alignas(16) short As[2][2048];   // [buf][row*64 + unit*8], 4KB each
    __shared__ alignas(16) short Bs[2][8192];   // [buf][n*64 + unit*8],  16KB each
    __shared__ float norms[2][2][16];

    auto STAGE = [&](int buf, int t) {
        {   // A: 32 rows x 8 16B-units = 256 slots, 1/thread; source-swizzled
            const int s   = tid;
            const int row = s >> 3;
            const int u   = (s & 7) ^ (row & 7);
            const short* ga = Ah + (size_t)(row0 + row) * HDIM + t * 64 + u * 8;
            __builtin_amdgcn_global_load_lds(
                (const __attribute__((address_space(1))) unsigned*)ga,
                (__attribute__((address_space(3))) unsigned*)((char*)&As[buf][0] + (size_t)(wave * 64) * 16),
                16, 0, 0);
        }
#pragma unroll
        for (int i = 0; i < 4; ++i) {   // B: 128 n x 8 units = 1024 slots
            const int sb = i * 256 + wave * 64;
            const int s  = sb + lane;
            const int n  = s >> 3;
            const int c8 = (s & 7) ^ (n & 7);
            const short* gb = Wbf + (size_t)n * HDIM + t * 64 + c8 * 8;
            __builtin_amdgcn_global_load_lds(
                (const __attribute__((address_space(1))) unsigned*)gb,
                (__attribute__((address_space(3))) unsigned*)((char*)&Bs[buf][0] + (size_t)sb * 16),
                16, 0, 0);
        }
    };

    f32x4 acc[4];
#pragma unroll
    for (int nt = 0; nt < 4; ++nt) acc[nt] = (f32x4){0.f, 0.f, 0.f, 0.f};

    STAGE(0, 0);
    __syncthreads();

    for (int t = 0; t < 12; ++t) {
        const int cur = t & 1;
        if (t < 11) STAGE(cur ^ 1, t + 1);     // fly under this step's compute

        const short* Ab = &As[cur][0];
        const short* Bb = &Bs[cur][0];
#pragma unroll
        for (int ks = 0; ks < 2; ++ks) {
            bf16x8 bfr[4];
#pragma unroll
            for (int nt = 0; nt < 4; ++nt) {
                const int nl = wc * 64 + nt * 16 + lc;
                const int c8 = (ks * 4 + g) ^ (nl & 7);    // read-side swizzle
                bfr[nt] = *(const bf16x8*)(Bb + (size_t)nl * 64 + c8 * 8);
            }
            const int rl = wr * 16 + lc;
            const int ua = (ks * 4 + g) ^ (rl & 7);        // read-side swizzle
            bf16x8 af = *(const bf16x8*)(Ab + (size_t)rl * 64 + ua * 8);
#pragma unroll
            for (int nt = 0; nt < 4; ++nt)
                acc[nt] = __builtin_amdgcn_mfma_f32_16x16x32_bf16(af, bfr[nt], acc[nt], 0, 0, 0);
        }
        __syncthreads();     // next tile landed; safe to overwrite cur next iter
    }

    // row norms: partial over this wave's 64 cols, combine col-halves via LDS
    float part[4];
#pragma unroll
    for (int i = 0; i < 4; ++i) {
        float s = 0.f;
#pragma unroll
        for (int nt = 0; nt < 4; ++nt) s += acc[nt][i] * acc[nt][i];
        s += __shfl_xor(s, 1);
        s += __shfl_xor(s, 2);
        s += __shfl_xor(s, 4);
        s += __shfl_xor(s, 8);
        part[i] = s;
    }
    if (lc == 0) {
#pragma unroll
        for (int i = 0; i < 4; ++i) norms[wr][wc][g * 4 + i] = part[i];
    }
    __syncthreads();

    short* Obase = (row0 < NTOK_Q) ? Qn + (size_t)row0 * DDIM
                                   : Dn + (size_t)(row0 - NTOK_Q) * DDIM;
#pragma unroll
    for (int i = 0; i < 4; ++i) {
        const int rloc = g * 4 + i;                     // within 16-row tile
        const float tot = norms[wr][0][rloc] + norms[wr][1][rloc];
        const float inv = 1.f / fmaxf(sqrtf(tot), 1e-12f);
        short* dst = Obase + (size_t)(wr * 16 + rloc) * DDIM + wc * 64;
#pragma unroll
        for (int nt = 0; nt < 4; ++nt)
            dst[nt * 16 + lc] = f2bf(acc[nt][i] * inv);
    }
}

// ---------------------------------------------------------------------------
// MaxSim (round-6 version, ~3.5us): block = (c, 8 b's), 8 waves; wave <-> one
// b. D[c] staged in 4 chunks of 64 rows, double-buffered, XOR-swizzled.
__global__ __launch_bounds__(512)
void maxsim(const short* __restrict__ Qn, const short* __restrict__ Dn,
            const unsigned short* __restrict__ maskT, float* __restrict__ out) {
    const int x  = blockIdx.x & 7;            // XCD (perf heuristic only)
    const int m8 = (blockIdx.x >> 3) & 7;
    const int bg = blockIdx.x >> 6;           // b-group (8 b's)
    const int c  = x * 8 + m8;                // all 8 bg's of a c on one XCD

    const int wave = threadIdx.x >> 6;        // 0..7  <-> local b
    const int lane = threadIdx.x & 63;
    const int g = lane >> 4, lc = lane & 15;

    __shared__ alignas(16) short Ds[2][4096 * 2];   // [buf][64 rows * 128], 16KB each

    const short* dsrc = Dn + (size_t)c * LDOC * DDIM;

    auto STAGE = [&](int buf, int ch) {
#pragma unroll
        for (int i = 0; i < 2; ++i) {
            const int sb = wave * 128 + i * 64;  // wave-uniform 16B-slot base
            const int s  = sb + lane;
            const int rowl = s >> 4;             // 0..63
            const int c16  = (s & 15) ^ (rowl & 15);
            const short* ga = dsrc + (size_t)(ch * 64 + rowl) * DDIM + c16 * 8;
            __builtin_amdgcn_global_load_lds(
                (const __attribute__((address_space(1))) unsigned*)ga,
                (__attribute__((address_space(3))) unsigned*)((char*)&Ds[buf][0] + (size_t)sb * 16),
                16, 0, 0);
        }
    };

    STAGE(0, 0);

    // Q fragments: this wave's 32 q-rows (one b), full K=128
    bf16x8 qf[2][4];
    const int qrow0 = bg * 256 + wave * 32;
#pragma unroll
    for (int m = 0; m < 2; ++m) {
        const short* qb = Qn + (size_t)(qrow0 + m * 16 + lc) * DDIM;
#pragma unroll
        for (int ks = 0; ks < 4; ++ks)
            qf[m][ks] = *(const bf16x8*)(qb + ks * 32 + g * 8);
    }
    const unsigned mbits = maskT[c * 16 + lc];    // bit nt = mask[c][nt*16+lc]

    __syncthreads();   // chunk 0 landed

    float rmax[2][4];
#pragma unroll
    for (int m = 0; m < 2; ++m)
#pragma unroll
        for (int i = 0; i < 4; ++i) rmax[m][i] = -INFINITY;

    for (int ch = 0; ch < 4; ++ch) {
        const int buf = ch & 1;
        if (ch < 3) STAGE(buf ^ 1, ch + 1);       // fly under this chunk's compute
        const short* Db = &Ds[buf][0];
#pragma unroll
        for (int j = 0; j < 4; ++j) {
            const int rowl = j * 16 + lc;
            bf16x8 bf[4];
#pragma unroll
            for (int ks = 0; ks < 4; ++ks) {
                const int c16 = (ks * 4 + g) ^ lc;     // read-side swizzle
                bf[ks] = *(const bf16x8*)(Db + (size_t)rowl * DDIM + c16 * 8);
            }
            const bool on = (mbits >> (ch * 4 + j)) & 1;
#pragma unroll
            for (int m = 0; m < 2; ++m) {
                f32x4 acc = (f32x4){0.f, 0.f, 0.f, 0.f};
#pragma unroll
                for (int ks = 0; ks < 4; ++ks)
                    acc = __builtin_amdgcn_mfma_f32_16x16x32_bf16(qf[m][ks], bf[ks], acc, 0, 0, 0);
#pragma unroll
                for (int i = 0; i < 4; ++i)
                    rmax[m][i] = on ? fmaxf(rmax[m][i], acc[i]) : rmax[m][i];
            }
        }
        __syncthreads();   // next chunk landed; this chunk's reads done block-wide
    }

    // cross-col max (16 lc lanes), then sum this wave's 32 rows
    float s = 0.f;
#pragma unroll
    for (int m = 0; m < 2; ++m)
#pragma unroll
        for (int i = 0; i < 4; ++i) {
            float r = rmax[m][i];
            r = fmaxf(r, __shfl_xor(r, 1));
            r = fmaxf(r, __shfl_xor(r, 2));
            r = fmaxf(r, __shfl_xor(r, 4));
            r = fmaxf(r, __shfl_xor(r, 8));
            s += r;
        }
    s += __shfl_xor(s, 16);
    s += __shfl_xor(s, 32);

    if (lane == 0) {
        const int b = bg * 8 + wave;
        out[(size_t)b * NB + c] = s;
    }
}

// ---------------------------------------------------------------------------
extern "C" void kernel_launch(void* const* d_in, const int* in_sizes, int n_in,
                              void* d_out, int out_size, void* d_ws, size_t ws_size,
                              hipStream_t stream) {
    const float* Qh = (const float*)d_in[0];
    const float* Dh = (const float*)d_in[1];
    const float* W  = (const float*)d_in[2];
    const unsigned char* dm = (const unsigned char*)d_in[3];
    float* out = (float*)d_out;
    char* ws = (char*)d_ws;

    short*          Wbf   = (short*)(ws + WS_OFF_W);
    unsigned short* maskT = (unsigned short*)(ws + WS_OFF_MASK);
    short*          Qn    = (short*)(ws + WS_OFF_QN);
    short*          Dn    = (short*)(ws + WS_OFF_DN);
    short*          Ah    = (short*)(ws + WS_OFF_AH);

    convert_prep<<<1825, 256, 0, stream>>>(Qh, Dh, W, Ah, Wbf, dm, maskT);
    proj_gemm<<<NTOK / 32, 256, 0, stream>>>(Ah, Wbf, Qn, Dn);
    maxsim<<<512, 512, 0, stream>>>(Qn, Dn, maskT, out);
}

// Round 10
// 41.517 us; speedup vs baseline: 1.2429x; 1.2429x over previous
//
#include <hip/hip_runtime.h>
#include <hip/hip_bf16.h>
#include <math.h>

typedef __attribute__((ext_vector_type(4))) float f32x4;
typedef __attribute__((ext_vector_type(8))) short bf16x8;

#define NB    64
#define LQ    32
#define LDOC  256
#define HDIM  768
#define DDIM  128
#define NTOK_Q (NB * LQ)        // 2048
#define NTOK_D (NB * LDOC)      // 16384
#define NTOK   (NTOK_Q + NTOK_D) // 18432

// ws layout (bytes):
#define WS_OFF_W    0           // Wbf   : 128*768 bf16   (196608)
#define WS_OFF_MASK 196608      // maskT : 64*16 ushort (2KB)
#define WS_OFF_QN   212992      // Qn    : 2048*128 bf16
#define WS_OFF_DN   737280      // Dn    : 16384*128 bf16

__device__ inline short f2bf(float f) {
    unsigned u = __float_as_uint(f);
    u = (u + 0x7fffu + ((u >> 16) & 1u)) >> 16;   // RNE
    return (short)u;
}

// ---------------------------------------------------------------------------
// prep: blocks 0..95 convert W fp32->bf16; block 96 builds bit-transposed mask.
__global__ void prep(const float* __restrict__ W, short* __restrict__ Wbf,
                     const unsigned char* __restrict__ mraw,
                     unsigned short* __restrict__ maskT) {
    if (blockIdx.x < 96) {
        int i = blockIdx.x * 256 + threadIdx.x;
        float4 v = *(const float4*)(W + (size_t)i * 4);
        short4 o;
        o.x = f2bf(v.x); o.y = f2bf(v.y); o.z = f2bf(v.z); o.w = f2bf(v.w);
        *(short4*)(Wbf + (size_t)i * 4) = o;
        return;
    }
    __shared__ int dword_ok_s;
    if (threadIdx.x == 0) dword_ok_s = 1;
    __syncthreads();
    const unsigned* dw = (const unsigned*)mraw;
    int ok = 1;
    for (int i = threadIdx.x; i < 4096; i += 256) {   // first 16KB: safe both ways
        unsigned v = dw[i];
        if (!(v == 0u || v == 1u || v == 0x3F800000u)) ok = 0;
    }
    if (!ok) atomicAnd(&dword_ok_s, 0);
    __syncthreads();
    const int isdw = dword_ok_s;
    for (int w = threadIdx.x; w < 1024; w += 256) {   // word w: c=w>>4, lane-col=w&15
        const int c = w >> 4, lcc = w & 15;
        unsigned bits = 0;
        if (isdw) {
            for (int nt = 0; nt < 16; ++nt)
                bits |= (dw[c * 256 + nt * 16 + lcc] ? 1u : 0u) << nt;
        } else {
            for (int nt = 0; nt < 16; ++nt)
                bits |= (mraw[c * 256 + nt * 16 + lcc] ? 1u : 0u) << nt;
        }
        maskT[w] = (unsigned short)bits;
    }
}

// ---------------------------------------------------------------------------
// Projection + L2 norm v10: REG-STAGED 2-phase pipeline (no global_load_lds).
// Block = 32 rows x 128 cols, BK=64, 12 steps, 4 waves (2x2 of 16x64).
// Per step/thread: issue 6 plain 16B global loads for tile t+1 BEFORE
// compute(t) (sched_barrier-pinned), convert + ds_write after compute,
// one barrier per step. LDS 40KB -> 4 blocks/CU.
__global__ __launch_bounds__(256)
void proj_norm(const float* __restrict__ Qh, const float* __restrict__ Dh,
               const short* __restrict__ Wbf,
               short* __restrict__ Qn, short* __restrict__ Dn) {
    const int tid  = threadIdx.x;
    const int lane = tid & 63;
    const int wave = tid >> 6;
    const int g    = lane >> 4;
    const int lc   = lane & 15;
    const int wr   = wave >> 1;          // 16-row half
    const int wc   = wave & 1;           // 64-col half
    const int row0 = blockIdx.x * 32;

    const float* Asrc = (row0 < NTOK_Q) ? Qh + (size_t)row0 * HDIM
                                        : Dh + (size_t)(row0 - NTOK_Q) * HDIM;

    __shared__ alignas(16) short As[2][2048];   // [buf][row*64 + unit*8], 4KB each
    __shared__ alignas(16) short Bs[2][8192];   // [buf][n*64 + unit*8],  16KB each
    __shared__ float norms[2][2][16];

    // --- per-thread staging assignment (static) ---
    // A: 32 rows x 8 units(16B of bf16 = 8 cols... as fp32: 32B) = 256 slots
    const int arow = tid >> 3, au = tid & 7;
    const float* aga  = Asrc + (size_t)arow * HDIM + au * 8;
    const int    adst = arow * 64 + (au ^ (arow & 7)) * 8;
    // B: 128 n x 8 units = 1024 slots, 4/thread
    const int n0 = tid >> 3,           u0 = tid & 7;
    const int n1 = (256 + tid) >> 3,   u1 = u0;
    const int n2 = (512 + tid) >> 3,   u2 = u0;
    const int n3 = (768 + tid) >> 3,   u3 = u0;
    const short* bga0 = Wbf + (size_t)n0 * HDIM + u0 * 8;
    const short* bga1 = Wbf + (size_t)n1 * HDIM + u1 * 8;
    const short* bga2 = Wbf + (size_t)n2 * HDIM + u2 * 8;
    const short* bga3 = Wbf + (size_t)n3 * HDIM + u3 * 8;
    const int bd0 = n0 * 64 + (u0 ^ (n0 & 7)) * 8;
    const int bd1 = n1 * 64 + (u1 ^ (n1 & 7)) * 8;
    const int bd2 = n2 * 64 + (u2 ^ (n2 & 7)) * 8;
    const int bd3 = n3 * 64 + (u3 ^ (n3 & 7)) * 8;

    float4 ar0, ar1;
    bf16x8 br0, br1, br2, br3;

    auto LOADS = [&](int t) {
        ar0 = *(const float4*)(aga + t * 64);
        ar1 = *(const float4*)(aga + t * 64 + 4);
        br0 = *(const bf16x8*)(bga0 + t * 64);
        br1 = *(const bf16x8*)(bga1 + t * 64);
        br2 = *(const bf16x8*)(bga2 + t * 64);
        br3 = *(const bf16x8*)(bga3 + t * 64);
    };
    auto WRITES = [&](int buf) {
        bf16x8 av;
        av[0] = f2bf(ar0.x); av[1] = f2bf(ar0.y); av[2] = f2bf(ar0.z); av[3] = f2bf(ar0.w);
        av[4] = f2bf(ar1.x); av[5] = f2bf(ar1.y); av[6] = f2bf(ar1.z); av[7] = f2bf(ar1.w);
        *(bf16x8*)(&As[buf][adst]) = av;
        *(bf16x8*)(&Bs[buf][bd0]) = br0;
        *(bf16x8*)(&Bs[buf][bd1]) = br1;
        *(bf16x8*)(&Bs[buf][bd2]) = br2;
        *(bf16x8*)(&Bs[buf][bd3]) = br3;
    };

    f32x4 acc[4];
#pragma unroll
    for (int nt = 0; nt < 4; ++nt) acc[nt] = (f32x4){0.f, 0.f, 0.f, 0.f};

    LOADS(0);
    WRITES(0);
    __syncthreads();

    for (int t = 0; t < 12; ++t) {
        const int cur = t & 1;
        if (t < 11) LOADS(t + 1);               // HBM latency hides under compute
        __builtin_amdgcn_sched_barrier(0);      // pin load issue above compute

        const short* Ab = &As[cur][0];
        const short* Bb = &Bs[cur][0];
#pragma unroll
        for (int ks = 0; ks < 2; ++ks) {
            bf16x8 bfr[4];
#pragma unroll
            for (int nt = 0; nt < 4; ++nt) {
                const int nl = wc * 64 + nt * 16 + lc;
                const int c8 = (ks * 4 + g) ^ (nl & 7);    // read-side swizzle
                bfr[nt] = *(const bf16x8*)(Bb + (size_t)nl * 64 + c8 * 8);
            }
            const int rl = wr * 16 + lc;
            const int ua = (ks * 4 + g) ^ (rl & 7);        // read-side swizzle
            bf16x8 af = *(const bf16x8*)(Ab + (size_t)rl * 64 + ua * 8);
#pragma unroll
            for (int nt = 0; nt < 4; ++nt)
                acc[nt] = __builtin_amdgcn_mfma_f32_16x16x32_bf16(af, bfr[nt], acc[nt], 0, 0, 0);
        }
        if (t < 11) WRITES(cur ^ 1);            // waits loads via reg dependency
        __syncthreads();
    }

    // row norms: partial over this wave's 64 cols, combine col-halves via LDS
    float part[4];
#pragma unroll
    for (int i = 0; i < 4; ++i) {
        float s = 0.f;
#pragma unroll
        for (int nt = 0; nt < 4; ++nt) s += acc[nt][i] * acc[nt][i];
        s += __shfl_xor(s, 1);
        s += __shfl_xor(s, 2);
        s += __shfl_xor(s, 4);
        s += __shfl_xor(s, 8);
        part[i] = s;
    }
    if (lc == 0) {
#pragma unroll
        for (int i = 0; i < 4; ++i) norms[wr][wc][g * 4 + i] = part[i];
    }
    __syncthreads();

    short* Obase = (row0 < NTOK_Q) ? Qn + (size_t)row0 * DDIM
                                   : Dn + (size_t)(row0 - NTOK_Q) * DDIM;
#pragma unroll
    for (int i = 0; i < 4; ++i) {
        const int rloc = g * 4 + i;                     // within 16-row tile
        const float tot = norms[wr][0][rloc] + norms[wr][1][rloc];
        const float inv = 1.f / fmaxf(sqrtf(tot), 1e-12f);
        short* dst = Obase + (size_t)(wr * 16 + rloc) * DDIM + wc * 64;
#pragma unroll
        for (int nt = 0; nt < 4; ++nt)
            dst[nt * 16 + lc] = f2bf(acc[nt][i] * inv);
    }
}

// ---------------------------------------------------------------------------
// MaxSim v5: reg-staged (no global_load_lds). Block = (c, 8 b's), 8 waves;
// wave <-> one b (32 q-rows x 256 n). D[c] in 4 chunks of 64 rows, double-
// buffered; per chunk/thread: 2 plain 16B loads issued before compute,
// 2 swizzled ds_writes after. LDS 32KB.
__global__ __launch_bounds__(512)
void maxsim(const short* __restrict__ Qn, const short* __restrict__ Dn,
            const unsigned short* __restrict__ maskT, float* __restrict__ out) {
    const int x  = blockIdx.x & 7;            // XCD (perf heuristic only)
    const int m8 = (blockIdx.x >> 3) & 7;
    const int bg = blockIdx.x >> 6;           // b-group (8 b's)
    const int c  = x * 8 + m8;                // all 8 bg's of a c on one XCD

    const int tid  = threadIdx.x;
    const int wave = tid >> 6;                // 0..7  <-> local b
    const int lane = tid & 63;
    const int g = lane >> 4, lc = lane & 15;

    __shared__ alignas(16) short Ds[2][8192];   // [buf][64 rows * 128], 16KB each

    const short* dsrc = Dn + (size_t)c * LDOC * DDIM;

    // staging: 64 rows x 16 units = 1024 slots, 2/thread
    const int r0 = tid >> 4,          v0 = tid & 15;
    const int r1 = (512 + tid) >> 4,  v1 = v0;
    const int dd0 = r0 * DDIM + (v0 ^ (r0 & 15)) * 8;
    const int dd1 = r1 * DDIM + (v1 ^ (r1 & 15)) * 8;
    bf16x8 dr0, dr1;

    auto LOADS = [&](int ch) {
        dr0 = *(const bf16x8*)(dsrc + (size_t)(ch * 64 + r0) * DDIM + v0 * 8);
        dr1 = *(const bf16x8*)(dsrc + (size_t)(ch * 64 + r1) * DDIM + v1 * 8);
    };
    auto WRITES = [&](int buf) {
        *(bf16x8*)(&Ds[buf][dd0]) = dr0;
        *(bf16x8*)(&Ds[buf][dd1]) = dr1;
    };

    LOADS(0);
    WRITES(0);

    // Q fragments: this wave's 32 q-rows (one b), full K=128
    bf16x8 qf[2][4];
    const int qrow0 = bg * 256 + wave * 32;
#pragma unroll
    for (int m = 0; m < 2; ++m) {
        const short* qb = Qn + (size_t)(qrow0 + m * 16 + lc) * DDIM;
#pragma unroll
        for (int ks = 0; ks < 4; ++ks)
            qf[m][ks] = *(const bf16x8*)(qb + ks * 32 + g * 8);
    }
    const unsigned mbits = maskT[c * 16 + lc];    // bit nt = mask[c][nt*16+lc]

    __syncthreads();   // chunk 0 written

    float rmax[2][4];
#pragma unroll
    for (int m = 0; m < 2; ++m)
#pragma unroll
        for (int i = 0; i < 4; ++i) rmax[m][i] = -INFINITY;

    for (int ch = 0; ch < 4; ++ch) {
        const int buf = ch & 1;
        if (ch < 3) LOADS(ch + 1);                // fly under this chunk's compute
        __builtin_amdgcn_sched_barrier(0);
        const short* Db = &Ds[buf][0];
#pragma unroll
        for (int j = 0; j < 4; ++j) {
            const int rowl = j * 16 + lc;
            bf16x8 bf[4];
#pragma unroll
            for (int ks = 0; ks < 4; ++ks) {
                const int c16 = (ks * 4 + g) ^ lc;     // read-side swizzle
                bf[ks] = *(const bf16x8*)(Db + (size_t)rowl * DDIM + c16 * 8);
            }
            const bool on = (mbits >> (ch * 4 + j)) & 1;
#pragma unroll
            for (int m = 0; m < 2; ++m) {
                f32x4 acc = (f32x4){0.f, 0.f, 0.f, 0.f};
#pragma unroll
                for (int ks = 0; ks < 4; ++ks)
                    acc = __builtin_amdgcn_mfma_f32_16x16x32_bf16(qf[m][ks], bf[ks], acc, 0, 0, 0);
#pragma unroll
                for (int i = 0; i < 4; ++i)
                    rmax[m][i] = on ? fmaxf(rmax[m][i], acc[i]) : rmax[m][i];
            }
        }
        if (ch < 3) WRITES(buf ^ 1);
        __syncthreads();
    }

    // cross-col max (16 lc lanes), then sum this wave's 32 rows
    float s = 0.f;
#pragma unroll
    for (int m = 0; m < 2; ++m)
#pragma unroll
        for (int i = 0; i < 4; ++i) {
            float r = rmax[m][i];
            r = fmaxf(r, __shfl_xor(r, 1));
            r = fmaxf(r, __shfl_xor(r, 2));
            r = fmaxf(r, __shfl_xor(r, 4));
            r = fmaxf(r, __shfl_xor(r, 8));
            s += r;
        }
    s += __shfl_xor(s, 16);
    s += __shfl_xor(s, 32);

    if (lane == 0) {
        const int b = bg * 8 + wave;
        out[(size_t)b * NB + c] = s;
    }
}

// ---------------------------------------------------------------------------
extern "C" void kernel_launch(void* const* d_in, const int* in_sizes, int n_in,
                              void* d_out, int out_size, void* d_ws, size_t ws_size,
                              hipStream_t stream) {
    const float* Qh = (const float*)d_in[0];
    const float* Dh = (const float*)d_in[1];
    const float* W  = (const float*)d_in[2];
    const unsigned char* dm = (const unsigned char*)d_in[3];
    float* out = (float*)d_out;
    char* ws = (char*)d_ws;

    short*          Wbf   = (short*)(ws + WS_OFF_W);
    unsigned short* maskT = (unsigned short*)(ws + WS_OFF_MASK);
    short*          Qn    = (short*)(ws + WS_OFF_QN);
    short*          Dn    = (short*)(ws + WS_OFF_DN);

    prep<<<97, 256, 0, stream>>>(W, Wbf, dm, maskT);
    proj_norm<<<NTOK / 32, 256, 0, stream>>>(Qh, Dh, Wbf, Qn, Dn);
    maxsim<<<512, 512, 0, stream>>>(Qn, Dn, maskT, out);
}